// Round 3
// baseline (195.069 us; speedup 1.0000x reference)
//
#include <hip/hip_runtime.h>
#include <hip/hip_bf16.h>
#include <stdint.h>

// Problem constants (fixed by setup_inputs)
#define NN 10000
#define EE 160000
#define BB 2
#define TT 12
#define FF 16
#define HG 32
#define HH 64
#define PP 4
#define BT (BB*TT)   // 24
#define MM (BB*NN)   // 20000
#define CAP 96       // fixed CSR capacity/node: deg ~ Binom(160k,1e-4), 20 sigma
#define L2E 1.4426950408889634f

typedef _Float16 half8 __attribute__((ext_vector_type(8)));
typedef _Float16 h2 __attribute__((ext_vector_type(2)));
typedef float f32x4 __attribute__((ext_vector_type(4)));

union UP { uint32_t u; h2 h; };
union H8U { uint32_t u[4]; half8 v; };

// a pre-scaled by log2(e): sigmoid(x) = rcp(1 + exp2(-L*x))
__device__ __forceinline__ float sigm2(float a) {
  return __builtin_amdgcn_rcpf(1.0f + __builtin_amdgcn_exp2f(-a));
}
// a pre-scaled by 2*log2(e): tanh(x) = 1 - 2*rcp(1 + exp2(2L*x))
__device__ __forceinline__ float tanh2(float a) {
  return fmaf(-2.0f, __builtin_amdgcn_rcpf(1.0f + __builtin_amdgcn_exp2f(a)), 1.0f);
}
// g-gate: returns (2*L2E)*tanh(x) where a = 2*L2E*x pre-scaled.
__device__ __forceinline__ float tanh2g(float a) {
  return fmaf(-2.0f * (2.0f * L2E),
              __builtin_amdgcn_rcpf(1.0f + __builtin_amdgcn_exp2f(a)),
              2.0f * L2E);
}

// lgkm-only barrier (proven neutral vs __syncthreads in r2, kept: never worse)
__device__ __forceinline__ void barrier_lds() {
  asm volatile("s_waitcnt lgkmcnt(0)" ::: "memory");
  __builtin_amdgcn_s_barrier();
  asm volatile("" ::: "memory");
}

// ---- merged: CSR build + era5 transpose + LSTM weight pre-pack ----
// wbuf layout: dword e of thread t at wbuf[e*256+t] (lane-interleaved).
//   e 0..3 bias1[g] | 4..7 bias2[g] | 8..11 wx[g]
//   e 12..27  Bx[g]      (4 dwords per half8)
//   e 28..59  Bh1[g][c2]
//   e 60..91  Bh2[g][c2]
#define FILL_BLKS (EE / 256)              // 625
#define PREP_BLKS ((NN * BT * 8) / 256)   // 7500
__global__ __launch_bounds__(256) void k_prepfill(
    const int* __restrict__ eidx, int* __restrict__ cnt, int* __restrict__ csr,
    const float* __restrict__ era5, uint32_t* __restrict__ xt,
    const float* __restrict__ w_ih1, const float* __restrict__ w_hh1,
    const float* __restrict__ b_ih1, const float* __restrict__ b_hh1,
    const float* __restrict__ w_ih2, const float* __restrict__ w_hh2,
    const float* __restrict__ b_ih2, const float* __restrict__ b_hh2,
    uint32_t* __restrict__ wbuf) {
  const int bid = blockIdx.x;
  const int tid = threadIdx.x;
  if (bid < FILL_BLKS) {
    int e = bid * 256 + tid;
    int d = eidx[EE + e];
    int pos = atomicAdd(&cnt[d], 1);
    if (pos < CAP) csr[d * CAP + pos] = eidx[e];
    return;
  }
  if (bid < FILL_BLKS + PREP_BLKS) {
    int D = (bid - FILL_BLKS) * 256 + tid;  // dword index
    int f2 = D & 7;
    int bt = (D >> 3) % BT;
    int n = D / (8 * BT);
    const float* src = era5 + ((size_t)bt * NN + n) * FF + f2 * 2;
    UP u; u.h[0] = (_Float16)src[0]; u.h[1] = (_Float16)src[1];
    xt[D] = u.u;
    return;
  }
  // ---- weight pre-pack (single block) ----
  const int wave = tid >> 6;
  const int lane = tid & 63;
  const int col = lane & 15;
  const int quad = lane >> 4;
#pragma unroll
  for (int g = 0; g < 4; ++g) {
    const float sc = (g == 2) ? 2.0f * L2E : L2E;
    int ncol = 16 * (wave + 4 * g) + col;
    wbuf[(0 + g) * 256 + tid] = __float_as_uint((b_ih1[ncol] + b_hh1[ncol]) * sc);
    wbuf[(4 + g) * 256 + tid] = __float_as_uint((b_ih2[ncol] + b_hh2[ncol]) * sc);
    wbuf[(8 + g) * 256 + tid] = __float_as_uint(w_ih2[ncol] * sc);
    H8U bx;
#pragma unroll
    for (int j = 0; j < 8; ++j)
      bx.v[j] = (_Float16)(w_ih1[ncol * HG + quad * 8 + j] * sc);
#pragma unroll
    for (int d = 0; d < 4; ++d) wbuf[(12 + g * 4 + d) * 256 + tid] = bx.u[d];
#pragma unroll
    for (int c2 = 0; c2 < 2; ++c2) {
      H8U b1, b2;
#pragma unroll
      for (int j = 0; j < 8; ++j) {
        b1.v[j] = (_Float16)(w_hh1[ncol * HH + c2 * 32 + quad * 8 + j] * sc);
        b2.v[j] = (_Float16)(w_hh2[ncol * HH + c2 * 32 + quad * 8 + j] * sc);
      }
#pragma unroll
      for (int d = 0; d < 4; ++d) {
        wbuf[(28 + (g * 2 + c2) * 4 + d) * 256 + tid] = b1.u[d];
        wbuf[(60 + (g * 2 + c2) * 4 + d) * 256 + tid] = b2.u[d];
      }
    }
  }
}

// ---- GCN aggregate on RAW features (768B/row) + fused W-apply (r8-proven) ----
__global__ __launch_bounds__(256) void k_gather(const uint32_t* __restrict__ xt,
                                                const int* __restrict__ csr,
                                                const int* __restrict__ cnt,
                                                const float* __restrict__ gw,
                                                const float* __restrict__ gb,
                                                uint32_t* __restrict__ gout) {
  __shared__ float wsm[FF * HG];     // 2 KB
  __shared__ float gbs[HG];
  __shared__ float agg[4][BT][FF];   // 6 KB
  const int tid = threadIdx.x;
  wsm[tid] = gw[tid];
  wsm[tid + 256] = gw[tid + 256];
  if (tid < HG) gbs[tid] = gb[tid];

  const int dloc = tid >> 6, lane = tid & 63;
  const int dst = blockIdx.x * 4 + dloc;
  const int cdst = min(cnt[dst], CAP);
  const float dinv_d = rsqrtf((float)cdst + 1.0f);

  float acc[6];
#pragma unroll
  for (int i = 0; i < 6; ++i) acc[i] = 0.f;

  for (int base = 0; base < cdst; base += 64) {
    int mine = base + lane;
    int sv = dst; float dvv = 0.f;   // padding: valid row, zero weight
    if (mine < cdst) {
      sv = csr[dst * CAP + mine];
      dvv = rsqrtf((float)cnt[sv] + 1.0f);
    }
    const int lim = min(64, cdst - base);
    for (int j = 0; j < lim; j += 4) {
      int sj[4]; float dj[4];
#pragma unroll
      for (int u = 0; u < 4; ++u) {
        int idx = j + u;
        sj[u] = __shfl(sv, idx);
        float d = __shfl(dvv, idx);
        dj[u] = (idx < lim) ? d : 0.f;
      }
      uint32_t dw[4][3];
#pragma unroll
      for (int u = 0; u < 4; ++u) {
        const uint32_t* row = xt + (size_t)sj[u] * 192;
#pragma unroll
        for (int k = 0; k < 3; ++k) dw[u][k] = row[lane + 64 * k];
      }
#pragma unroll
      for (int u = 0; u < 4; ++u) {
#pragma unroll
        for (int k = 0; k < 3; ++k) {
          UP up; up.u = dw[u][k];
          acc[2 * k]     = fmaf((float)up.h[0], dj[u], acc[2 * k]);
          acc[2 * k + 1] = fmaf((float)up.h[1], dj[u], acc[2 * k + 1]);
        }
      }
    }
  }
  const uint32_t* srow = xt + (size_t)dst * 192;
#pragma unroll
  for (int k = 0; k < 3; ++k) {
    UP u; u.u = srow[lane + 64 * k];
    int d0 = lane + 64 * k;
    int bt = d0 >> 3, f = (d0 & 7) * 2;
    agg[dloc][bt][f]     = (acc[2 * k]     + (float)u.h[0] * dinv_d) * dinv_d;
    agg[dloc][bt][f + 1] = (acc[2 * k + 1] + (float)u.h[1] * dinv_d) * dinv_d;
  }
  __syncthreads();
#pragma unroll
  for (int k = 0; k < 3; ++k) {
    int d0 = lane + 64 * k;
    int t = d0 >> 4, c0 = (d0 & 15) * 2;
#pragma unroll
    for (int b = 0; b < 2; ++b) {
      const float* av = agg[dloc][b * TT + t];
      float v0 = gbs[c0], v1 = gbs[c0 + 1];
#pragma unroll
      for (int f = 0; f < FF; ++f) {
        v0 = fmaf(av[f], wsm[f * HG + c0], v0);
        v1 = fmaf(av[f], wsm[f * HG + c0 + 1], v1);
      }
      UP u; u.h[0] = (_Float16)v0; u.h[1] = (_Float16)v1;
      gout[((size_t)(b * NN + dst)) * 192 + d0] = u.u;
    }
  }
}

// -------- fused dual LSTM + FC; 32 m-rows/block = 2 independent MFMA tiles --------
// r2 counters: 1.33 waves/SIMD x 43% issue rate = 57% VALUBusy -> latency-bound
// at low residency. Fix: 2x ILP per thread (16 indep activation chains, 2 MFMA
// streams) + grid 1250->625 (~2.44 blk/CU, ~single residency round). Weights
// shared across tiles; one barrier per t serves both. No min-wave bound (r1
// spill lesson). FC buffer aliases h-exchange buffers (disjoint in time).
__global__ __launch_bounds__(256) void k_lstmfc(
    const _Float16* __restrict__ gout, const float* __restrict__ zeta,
    const uint32_t* __restrict__ wbuf,
    const float* __restrict__ fc_w, const float* __restrict__ fc_b,
    float* __restrict__ out) {
  const int m0 = blockIdx.x * 32;
  const int tid = threadIdx.x;
  const int wave = tid >> 6;
  const int lane = tid & 63;
  const int col = lane & 15;
  const int quad = lane >> 4;

  // coalesced prologue: 92 dword loads, zero VALU
  float bias1[4], bias2[4], wx[4];
  H8U Bx[4], Bh1[4][2], Bh2[4][2];
#pragma unroll
  for (int g = 0; g < 4; ++g) {
    bias1[g] = __uint_as_float(wbuf[(0 + g) * 256 + tid]);
    bias2[g] = __uint_as_float(wbuf[(4 + g) * 256 + tid]);
    wx[g]    = __uint_as_float(wbuf[(8 + g) * 256 + tid]);
#pragma unroll
    for (int d = 0; d < 4; ++d) Bx[g].u[d] = wbuf[(12 + g * 4 + d) * 256 + tid];
#pragma unroll
    for (int c2 = 0; c2 < 2; ++c2)
#pragma unroll
      for (int d = 0; d < 4; ++d) {
        Bh1[g][c2].u[d] = wbuf[(28 + (g * 2 + c2) * 4 + d) * 256 + tid];
        Bh2[g][c2].u[d] = wbuf[(60 + (g * 2 + c2) * 4 + d) * 256 + tid];
      }
  }
  // loop-invariant MFMA C-operand bias vectors
  f32x4 bv1[4];
#pragma unroll
  for (int g = 0; g < 4; ++g) {
    f32x4 v = {bias1[g], bias1[g], bias1[g], bias1[g]};
    bv1[g] = v;
  }

  // LDS: h-exchange double-buffers (2 tiles = 32 rows) aliased with FC buffer
  __shared__ union {
    struct {
      __align__(16) _Float16 hb1[2][32 * 72];
      __align__(16) _Float16 hb2[2][32 * 72];
    } h;                       // 18432 B
    float fcb[32][132];        // 16896 B
  } su;
  __shared__ float zbuf[TT][32];

  // zeta staging; per-ROW batch index (block 312 straddles b boundary)
  for (int i = tid; i < TT * 32; i += 256) {
    int t = i >> 5, s = i & 31;
    int m = m0 + s;
    int bs = (m >= NN) ? 1 : 0;
    int ns = m - bs * NN;
    zbuf[t][s] = zeta[((size_t)bs * TT + t) * NN + ns];
  }

  const _Float16* gbaseA = gout + (size_t)(m0 + col) * (TT * HG) + quad * 8;
  const _Float16* gbaseB = gbaseA + (size_t)16 * (TT * HG);
  half8 A0A = *(const half8*)(gbaseA);
  half8 A0B = *(const half8*)(gbaseB);

  // cell state carried pre-scaled by 2*L2E (see tanh2g)
  float c1A[4] = {0.f, 0.f, 0.f, 0.f}, c2A[4] = {0.f, 0.f, 0.f, 0.f};
  float c1B[4] = {0.f, 0.f, 0.f, 0.f}, c2B[4] = {0.f, 0.f, 0.f, 0.f};
  float h1fA[4], h2fA[4], h1fB[4], h2fB[4];

  barrier_lds();   // zbuf visible

#pragma unroll
  for (int t = 0; t < TT; ++t) {
    const int p = t & 1;
    if (t > 0) {
#pragma unroll
      for (int r = 0; r < 4; ++r) {
        int a = (quad * 4 + r) * 72 + 16 * wave + col;
        su.h.hb1[p][a] = (_Float16)h1fA[r];
        su.h.hb2[p][a] = (_Float16)h2fA[r];
        su.h.hb1[p][a + 16 * 72] = (_Float16)h1fB[r];
        su.h.hb2[p][a + 16 * 72] = (_Float16)h2fB[r];
      }
    }
    f32x4 a1A[4], a2A[4], a1B[4], a2B[4];
    const f32x4 z4A = *(const f32x4*)(&zbuf[t][quad * 4]);
    const f32x4 z4B = *(const f32x4*)(&zbuf[t][16 + quad * 4]);
#pragma unroll
    for (int g = 0; g < 4; ++g) {
      a1A[g] = __builtin_amdgcn_mfma_f32_16x16x32_f16(A0A, Bx[g].v, bv1[g], 0, 0, 0);
      a1B[g] = __builtin_amdgcn_mfma_f32_16x16x32_f16(A0B, Bx[g].v, bv1[g], 0, 0, 0);
#pragma unroll
      for (int r = 0; r < 4; ++r) {
        a2A[g][r] = fmaf(wx[g], z4A[r], bias2[g]);
        a2B[g][r] = fmaf(wx[g], z4B[r], bias2[g]);
      }
    }
    if (t < TT - 1) {
      A0A = *(const half8*)(gbaseA + (t + 1) * HG);
      A0B = *(const half8*)(gbaseB + (t + 1) * HG);
    }
    if (t > 0) {
      barrier_lds();
      const half8 A11A = *(const half8*)(&su.h.hb1[p][col * 72 + quad * 8]);
      const half8 A21A = *(const half8*)(&su.h.hb1[p][col * 72 + 32 + quad * 8]);
      const half8 A12A = *(const half8*)(&su.h.hb2[p][col * 72 + quad * 8]);
      const half8 A22A = *(const half8*)(&su.h.hb2[p][col * 72 + 32 + quad * 8]);
      const half8 A11B = *(const half8*)(&su.h.hb1[p][(16 + col) * 72 + quad * 8]);
      const half8 A21B = *(const half8*)(&su.h.hb1[p][(16 + col) * 72 + 32 + quad * 8]);
      const half8 A12B = *(const half8*)(&su.h.hb2[p][(16 + col) * 72 + quad * 8]);
      const half8 A22B = *(const half8*)(&su.h.hb2[p][(16 + col) * 72 + 32 + quad * 8]);
#pragma unroll
      for (int g = 0; g < 4; ++g) {
        a1A[g] = __builtin_amdgcn_mfma_f32_16x16x32_f16(A11A, Bh1[g][0].v, a1A[g], 0, 0, 0);
        a1A[g] = __builtin_amdgcn_mfma_f32_16x16x32_f16(A21A, Bh1[g][1].v, a1A[g], 0, 0, 0);
        a1B[g] = __builtin_amdgcn_mfma_f32_16x16x32_f16(A11B, Bh1[g][0].v, a1B[g], 0, 0, 0);
        a1B[g] = __builtin_amdgcn_mfma_f32_16x16x32_f16(A21B, Bh1[g][1].v, a1B[g], 0, 0, 0);
        a2A[g] = __builtin_amdgcn_mfma_f32_16x16x32_f16(A12A, Bh2[g][0].v, a2A[g], 0, 0, 0);
        a2A[g] = __builtin_amdgcn_mfma_f32_16x16x32_f16(A22A, Bh2[g][1].v, a2A[g], 0, 0, 0);
        a2B[g] = __builtin_amdgcn_mfma_f32_16x16x32_f16(A12B, Bh2[g][0].v, a2B[g], 0, 0, 0);
        a2B[g] = __builtin_amdgcn_mfma_f32_16x16x32_f16(A22B, Bh2[g][1].v, a2B[g], 0, 0, 0);
      }
    }
#pragma unroll
    for (int r = 0; r < 4; ++r) {
      // tile A, LSTM1
      float i1 = sigm2(a1A[0][r]), f1 = sigm2(a1A[1][r]);
      float g1 = tanh2g(a1A[2][r]), o1 = sigm2(a1A[3][r]);
      c1A[r] = fmaf(f1, c1A[r], i1 * g1);
      h1fA[r] = o1 * tanh2(c1A[r]);
      // tile A, LSTM2
      float i2 = sigm2(a2A[0][r]), f2 = sigm2(a2A[1][r]);
      float g2 = tanh2g(a2A[2][r]), o2 = sigm2(a2A[3][r]);
      c2A[r] = fmaf(f2, c2A[r], i2 * g2);
      h2fA[r] = o2 * tanh2(c2A[r]);
      // tile B, LSTM1
      float i3 = sigm2(a1B[0][r]), f3 = sigm2(a1B[1][r]);
      float g3 = tanh2g(a1B[2][r]), o3 = sigm2(a1B[3][r]);
      c1B[r] = fmaf(f3, c1B[r], i3 * g3);
      h1fB[r] = o3 * tanh2(c1B[r]);
      // tile B, LSTM2
      float i4 = sigm2(a2B[0][r]), f4 = sigm2(a2B[1][r]);
      float g4 = tanh2g(a2B[2][r]), o4 = sigm2(a2B[3][r]);
      c2B[r] = fmaf(f4, c2B[r], i4 * g4);
      h2fB[r] = o4 * tanh2(c2B[r]);
    }
  }
  // fcb aliases hb1/hb2: barrier so all waves' last hb reads complete first
  barrier_lds();
#pragma unroll
  for (int r = 0; r < 4; ++r) {
    su.fcb[quad * 4 + r][16 * wave + col] = h1fA[r];
    su.fcb[quad * 4 + r][64 + 16 * wave + col] = h2fA[r];
    su.fcb[16 + quad * 4 + r][16 * wave + col] = h1fB[r];
    su.fcb[16 + quad * 4 + r][64 + 16 * wave + col] = h2fB[r];
  }
  barrier_lds();
  if (tid < 128) {
    int pp = tid >> 5, s = tid & 31;
    int m = m0 + s;
    int bs = (m >= NN) ? 1 : 0;
    int ns = m - bs * NN;
    const f32x4* wr = (const f32x4*)(fc_w + pp * 128);
    const float* hv = su.fcb[s];
    float acc = fc_b[pp];
#pragma unroll
    for (int k = 0; k < 32; ++k) {
      f32x4 w4 = wr[k];
      acc += w4[0] * hv[4 * k] + w4[1] * hv[4 * k + 1] +
             w4[2] * hv[4 * k + 2] + w4[3] * hv[4 * k + 3];
    }
    out[((size_t)(bs * PP + pp)) * NN + ns] = acc;
  }
}

extern "C" void kernel_launch(void* const* d_in, const int* in_sizes, int n_in,
                              void* d_out, int out_size, void* d_ws, size_t ws_size,
                              hipStream_t stream) {
  (void)in_sizes; (void)n_in; (void)out_size; (void)ws_size;
  const float* era5  = (const float*)d_in[0];
  const float* zeta  = (const float*)d_in[1];
  const int*   eidx  = (const int*)d_in[2];
  const float* gcn_w = (const float*)d_in[3];
  const float* gcn_b = (const float*)d_in[4];
  const float* w_ih1 = (const float*)d_in[5];
  const float* w_hh1 = (const float*)d_in[6];
  const float* b_ih1 = (const float*)d_in[7];
  const float* b_hh1 = (const float*)d_in[8];
  const float* w_ih2 = (const float*)d_in[9];
  const float* w_hh2 = (const float*)d_in[10];
  const float* b_ih2 = (const float*)d_in[11];
  const float* b_hh2 = (const float*)d_in[12];
  const float* fc_w  = (const float*)d_in[13];
  const float* fc_b  = (const float*)d_in[14];
  float* out = (float*)d_out;

  char* ws = (char*)d_ws;
  int*      cnt  = (int*)(ws);                        // 40 KB
  int*      csr  = (int*)(ws + (64 << 10));           // 3.84 MB
  uint32_t* xt   = (uint32_t*)(ws + (4ull << 20));    // [N][BT][F] fp16, 7.68 MB
  uint32_t* gout = (uint32_t*)(ws + (12ull << 20));   // [B*N][T][HG] fp16, 15.36 MB
  uint32_t* wbuf = (uint32_t*)(ws + (28ull << 20));   // 92*256*4 = 94 KB

  hipMemsetAsync(cnt, 0, NN * sizeof(int), stream);
  k_prepfill<<<FILL_BLKS + PREP_BLKS + 1, 256, 0, stream>>>(
      eidx, cnt, csr, era5, xt,
      w_ih1, w_hh1, b_ih1, b_hh1, w_ih2, w_hh2, b_ih2, b_hh2, wbuf);
  k_gather<<<NN / 4, 256, 0, stream>>>(xt, csr, cnt, gcn_w, gcn_b, gout);
  k_lstmfc<<<MM / 32, 256, 0, stream>>>((const _Float16*)gout, zeta, wbuf,
                                        fc_w, fc_b, out);
}

// Round 4
// 176.725 us; speedup vs baseline: 1.1038x; 1.1038x over previous
//
#include <hip/hip_runtime.h>
#include <hip/hip_bf16.h>
#include <stdint.h>

// Problem constants (fixed by setup_inputs)
#define NN 10000
#define EE 160000
#define BB 2
#define TT 12
#define FF 16
#define HG 32
#define HH 64
#define PP 4
#define BT (BB*TT)   // 24
#define MM (BB*NN)   // 20000
#define CAP 96       // fixed CSR capacity/node: deg ~ Binom(160k,1e-4), 20 sigma
#define L2E 1.4426950408889634f

typedef _Float16 half8 __attribute__((ext_vector_type(8)));
typedef _Float16 h2 __attribute__((ext_vector_type(2)));
typedef float f32x4 __attribute__((ext_vector_type(4)));

union UP { uint32_t u; h2 h; };
union H8U { uint32_t u[4]; half8 v; };

// a pre-scaled by log2(e): sigmoid(x) = rcp(1 + exp2(-L*x))
__device__ __forceinline__ float sigm2(float a) {
  return __builtin_amdgcn_rcpf(1.0f + __builtin_amdgcn_exp2f(-a));
}
// a pre-scaled by 2*log2(e): tanh(x) = 1 - 2*rcp(1 + exp2(2L*x))
__device__ __forceinline__ float tanh2(float a) {
  return fmaf(-2.0f, __builtin_amdgcn_rcpf(1.0f + __builtin_amdgcn_exp2f(a)), 1.0f);
}
// g-gate: returns (2*L2E)*tanh(x); lets c be carried pre-scaled by 2*L2E.
__device__ __forceinline__ float tanh2g(float a) {
  return fmaf(-2.0f * (2.0f * L2E),
              __builtin_amdgcn_rcpf(1.0f + __builtin_amdgcn_exp2f(a)),
              2.0f * L2E);
}

// lgkm-only barrier (neutral vs __syncthreads per r2 A/B; never worse)
__device__ __forceinline__ void barrier_lds() {
  asm volatile("s_waitcnt lgkmcnt(0)" ::: "memory");
  __builtin_amdgcn_s_barrier();
  asm volatile("" ::: "memory");
}

// ---- merged: CSR build + era5 transpose + LSTM weight pre-pack ----
// wbuf layout: dword e of thread t at wbuf[e*256+t] (lane-interleaved).
//   e 0..3 bias1[g] | 4..7 bias2[g] | 8..11 wx[g]
//   e 12..27  Bx[g]      (4 dwords per half8)
//   e 28..59  Bh1[g][c2]
//   e 60..91  Bh2[g][c2]
//   e 92..99  Bg[nt]     (gcn_w as K=32-padded B-fragments, f16, k>=16 zero)
#define FILL_BLKS (EE / 256)              // 625
#define PREP_BLKS ((NN * BT * 8) / 256)   // 7500
__global__ __launch_bounds__(256) void k_prepfill(
    const int* __restrict__ eidx, int* __restrict__ cnt, int* __restrict__ csr,
    const float* __restrict__ era5, uint32_t* __restrict__ xt,
    const float* __restrict__ gcn_w,
    const float* __restrict__ w_ih1, const float* __restrict__ w_hh1,
    const float* __restrict__ b_ih1, const float* __restrict__ b_hh1,
    const float* __restrict__ w_ih2, const float* __restrict__ w_hh2,
    const float* __restrict__ b_ih2, const float* __restrict__ b_hh2,
    uint32_t* __restrict__ wbuf) {
  const int bid = blockIdx.x;
  const int tid = threadIdx.x;
  if (bid < FILL_BLKS) {
    int e = bid * 256 + tid;
    int d = eidx[EE + e];
    int pos = atomicAdd(&cnt[d], 1);
    if (pos < CAP) csr[d * CAP + pos] = eidx[e];
    return;
  }
  if (bid < FILL_BLKS + PREP_BLKS) {
    int D = (bid - FILL_BLKS) * 256 + tid;  // dword index
    int f2 = D & 7;
    int bt = (D >> 3) % BT;
    int n = D / (8 * BT);
    const float* src = era5 + ((size_t)bt * NN + n) * FF + f2 * 2;
    UP u; u.h[0] = (_Float16)src[0]; u.h[1] = (_Float16)src[1];
    xt[D] = u.u;
    return;
  }
  // ---- weight pre-pack (single block) ----
  const int wave = tid >> 6;
  const int lane = tid & 63;
  const int col = lane & 15;
  const int quad = lane >> 4;
#pragma unroll
  for (int g = 0; g < 4; ++g) {
    const float sc = (g == 2) ? 2.0f * L2E : L2E;
    int ncol = 16 * (wave + 4 * g) + col;
    wbuf[(0 + g) * 256 + tid] = __float_as_uint((b_ih1[ncol] + b_hh1[ncol]) * sc);
    wbuf[(4 + g) * 256 + tid] = __float_as_uint((b_ih2[ncol] + b_hh2[ncol]) * sc);
    wbuf[(8 + g) * 256 + tid] = __float_as_uint(w_ih2[ncol] * sc);
    H8U bx;
#pragma unroll
    for (int j = 0; j < 8; ++j)
      bx.v[j] = (_Float16)(w_ih1[ncol * HG + quad * 8 + j] * sc);
#pragma unroll
    for (int d = 0; d < 4; ++d) wbuf[(12 + g * 4 + d) * 256 + tid] = bx.u[d];
#pragma unroll
    for (int c2 = 0; c2 < 2; ++c2) {
      H8U b1, b2;
#pragma unroll
      for (int j = 0; j < 8; ++j) {
        b1.v[j] = (_Float16)(w_hh1[ncol * HH + c2 * 32 + quad * 8 + j] * sc);
        b2.v[j] = (_Float16)(w_hh2[ncol * HH + c2 * 32 + quad * 8 + j] * sc);
      }
#pragma unroll
      for (int d = 0; d < 4; ++d) {
        wbuf[(28 + (g * 2 + c2) * 4 + d) * 256 + tid] = b1.u[d];
        wbuf[(60 + (g * 2 + c2) * 4 + d) * 256 + tid] = b2.u[d];
      }
    }
  }
  // gcn_w B-fragments: B[k][n], k=f (0..15 valid, 16..31 zero), n = nt*16+col
#pragma unroll
  for (int nt = 0; nt < 2; ++nt) {
#pragma unroll
    for (int d = 0; d < 4; ++d) {
      int k0 = quad * 8 + d * 2;
      int c = nt * 16 + col;
      UP u;
      u.h[0] = (k0 < FF)     ? (_Float16)gcn_w[k0 * HG + c]       : (_Float16)0.f;
      u.h[1] = (k0 + 1 < FF) ? (_Float16)gcn_w[(k0 + 1) * HG + c] : (_Float16)0.f;
      wbuf[(92 + nt * 4 + d) * 256 + tid] = u.u;
    }
  }
}

// ---- GCN aggregate on RAW features (768B/row) + MFMA W-apply epilogue ----
// r3 analysis: old epilogue = ~300 scalar LDS reads + ~200 FMA per thread;
// replaced by 4 MFMAs on a wave-private f16 agg tile (zero-padded to K=32,
// M=32). No block barrier needed: each wave only touches aggh[dloc].
__global__ __launch_bounds__(256) void k_gather(const uint32_t* __restrict__ xt,
                                                const int* __restrict__ csr,
                                                const int* __restrict__ cnt,
                                                const float* __restrict__ gb,
                                                const uint32_t* __restrict__ wbuf,
                                                _Float16* __restrict__ gout) {
  // rows 24..31 and cols 16..31 stay zero (M-pad, K-pad); stride 40 f16 = 80B
  // keeps ds_read_b128 16B-aligned and ~conflict-free (2-way max).
  __shared__ __align__(16) _Float16 aggh[4][32][40];   // 10240 B
  const int tid = threadIdx.x;
  const int dloc = tid >> 6, lane = tid & 63;
  const int col = lane & 15, quad = lane >> 4;

  // zero own slice (640 dwords per wave, 10 per lane) — wave-private, no barrier
  uint32_t* az = (uint32_t*)&aggh[dloc][0][0];
#pragma unroll
  for (int i = 0; i < 10; ++i) az[lane + 64 * i] = 0u;

  // prepacked gcn_w B-fragments + bias (per-lane, identical across waves)
  H8U Bg[2];
#pragma unroll
  for (int nt = 0; nt < 2; ++nt)
#pragma unroll
    for (int d = 0; d < 4; ++d) Bg[nt].u[d] = wbuf[(92 + nt * 4 + d) * 256 + tid];
  const float b0 = gb[col], b1 = gb[16 + col];

  const int dst = blockIdx.x * 4 + dloc;
  const int cdst = min(cnt[dst], CAP);
  const float dinv_d = rsqrtf((float)cdst + 1.0f);

  float acc[6];
#pragma unroll
  for (int i = 0; i < 6; ++i) acc[i] = 0.f;

  for (int base = 0; base < cdst; base += 64) {
    int mine = base + lane;
    int sv = dst; float dvv = 0.f;   // padding: valid row, zero weight
    if (mine < cdst) {
      sv = csr[dst * CAP + mine];
      dvv = rsqrtf((float)cnt[sv] + 1.0f);
    }
    const int lim = min(64, cdst - base);
    for (int j = 0; j < lim; j += 4) {
      int sj[4]; float dj[4];
#pragma unroll
      for (int u = 0; u < 4; ++u) {
        int idx = j + u;
        sj[u] = __shfl(sv, idx);
        float d = __shfl(dvv, idx);
        dj[u] = (idx < lim) ? d : 0.f;
      }
      uint32_t dw[4][3];
#pragma unroll
      for (int u = 0; u < 4; ++u) {
        const uint32_t* row = xt + (size_t)sj[u] * 192;
#pragma unroll
        for (int k = 0; k < 3; ++k) dw[u][k] = row[lane + 64 * k];
      }
#pragma unroll
      for (int u = 0; u < 4; ++u) {
#pragma unroll
        for (int k = 0; k < 3; ++k) {
          UP up; up.u = dw[u][k];
          acc[2 * k]     = fmaf((float)up.h[0], dj[u], acc[2 * k]);
          acc[2 * k + 1] = fmaf((float)up.h[1], dj[u], acc[2 * k + 1]);
        }
      }
    }
  }
  // self term + symmetric normalization; store agg as f16 pairs (wave-private)
  const uint32_t* srow = xt + (size_t)dst * 192;
#pragma unroll
  for (int k = 0; k < 3; ++k) {
    UP u; u.u = srow[lane + 64 * k];
    int d0 = lane + 64 * k;
    int bt = d0 >> 3, f = (d0 & 7) * 2;
    UP o;
    o.h[0] = (_Float16)((acc[2 * k]     + (float)u.h[0] * dinv_d) * dinv_d);
    o.h[1] = (_Float16)((acc[2 * k + 1] + (float)u.h[1] * dinv_d) * dinv_d);
    *(uint32_t*)&aggh[dloc][bt][f] = o.u;
  }
  // same-wave LDS readback (compiler inserts lgkm wait); A-frag: m=col, k=quad*8+j
  f32x4 C[2][2];
#pragma unroll
  for (int mt = 0; mt < 2; ++mt) {
    const half8 Af = *(const half8*)&aggh[dloc][mt * 16 + col][quad * 8];
#pragma unroll
    for (int nt = 0; nt < 2; ++nt) {
      float bb = nt ? b1 : b0;
      f32x4 ci; ci[0] = bb; ci[1] = bb; ci[2] = bb; ci[3] = bb;
      C[mt][nt] = __builtin_amdgcn_mfma_f32_16x16x32_f16(Af, Bg[nt].v, ci, 0, 0, 0);
    }
  }
  // C layout: row(bt) = (lane>>4)*4 + r, col(c) = lane&15
#pragma unroll
  for (int mt = 0; mt < 2; ++mt)
#pragma unroll
    for (int r = 0; r < 4; ++r) {
      int bt = mt * 16 + quad * 4 + r;
      if (bt < BT) {
        int bb = (bt >= TT) ? 1 : 0;
        int t = bt - bb * TT;
#pragma unroll
        for (int nt = 0; nt < 2; ++nt) {
          int c = nt * 16 + col;
          gout[((size_t)(bb * NN + dst)) * 384 + t * 32 + c] = (_Float16)C[mt][nt][r];
        }
      }
    }
}

// -------- fused dual LSTM + FC; r2 structure (16 rows, 4 waves, grid 1250) --------
// Single change vs r2: FC buffer aliases the h-exchange buffers (disjoint in
// time; one barrier protects the alias). LDS 18432 -> ~10.2 KB — probes whether
// LDS caps block residency. No min-wave bound (r1 spill lesson).
__global__ __launch_bounds__(256) void k_lstmfc(
    const _Float16* __restrict__ gout, const float* __restrict__ zeta,
    const uint32_t* __restrict__ wbuf,
    const float* __restrict__ fc_w, const float* __restrict__ fc_b,
    float* __restrict__ out) {
  const int m0 = blockIdx.x * 16;
  const int b = (m0 >= NN) ? 1 : 0;
  const int n0 = m0 - b * NN;
  const int tid = threadIdx.x;
  const int wave = tid >> 6;
  const int lane = tid & 63;
  const int col = lane & 15;
  const int quad = lane >> 4;

  // coalesced prologue: 92 dword loads, zero VALU
  float bias1[4], bias2[4], wx[4];
  H8U Bx[4], Bh1[4][2], Bh2[4][2];
#pragma unroll
  for (int g = 0; g < 4; ++g) {
    bias1[g] = __uint_as_float(wbuf[(0 + g) * 256 + tid]);
    bias2[g] = __uint_as_float(wbuf[(4 + g) * 256 + tid]);
    wx[g]    = __uint_as_float(wbuf[(8 + g) * 256 + tid]);
#pragma unroll
    for (int d = 0; d < 4; ++d) Bx[g].u[d] = wbuf[(12 + g * 4 + d) * 256 + tid];
#pragma unroll
    for (int c2 = 0; c2 < 2; ++c2)
#pragma unroll
      for (int d = 0; d < 4; ++d) {
        Bh1[g][c2].u[d] = wbuf[(28 + (g * 2 + c2) * 4 + d) * 256 + tid];
        Bh2[g][c2].u[d] = wbuf[(60 + (g * 2 + c2) * 4 + d) * 256 + tid];
      }
  }
  // loop-invariant MFMA C-operand bias vectors
  f32x4 bv1[4];
#pragma unroll
  for (int g = 0; g < 4; ++g) {
    f32x4 v = {bias1[g], bias1[g], bias1[g], bias1[g]};
    bv1[g] = v;
  }

  // LDS: h-exchange double-buffers aliased with FC buffer (disjoint in time)
  __shared__ union {
    struct {
      __align__(16) _Float16 hb1[2][16 * 72];
      __align__(16) _Float16 hb2[2][16 * 72];
    } h;                       // 9216 B
    float fcb[16][132];        // 8448 B
  } su;
  __shared__ float zbuf[TT][16];

  if (tid < TT * 16) {
    int t = tid >> 4, s = tid & 15;
    zbuf[t][s] = zeta[((size_t)b * TT + t) * NN + n0 + s];
  }

  const _Float16* gbase = gout + (size_t)(m0 + col) * (TT * HG) + quad * 8;
  half8 A0 = *(const half8*)(gbase);

  // cell state carried pre-scaled by 2*L2E (see tanh2g)
  float c1[4] = {0.f, 0.f, 0.f, 0.f}, c2v[4] = {0.f, 0.f, 0.f, 0.f};
  float h1f[4], h2f[4];

  barrier_lds();   // zbuf visible; A0/weight prefetches stay in flight

#pragma unroll
  for (int t = 0; t < TT; ++t) {
    const int p = t & 1;
    if (t > 0) {
#pragma unroll
      for (int r = 0; r < 4; ++r) {
        int a = (quad * 4 + r) * 72 + 16 * wave + col;
        su.h.hb1[p][a] = (_Float16)h1f[r];
        su.h.hb2[p][a] = (_Float16)h2f[r];
      }
    }
    f32x4 a1[4], a2[4];
    const f32x4 z4 = *(const f32x4*)(&zbuf[t][quad * 4]);
#pragma unroll
    for (int g = 0; g < 4; ++g) {
      a1[g] = __builtin_amdgcn_mfma_f32_16x16x32_f16(A0, Bx[g].v, bv1[g], 0, 0, 0);
#pragma unroll
      for (int r = 0; r < 4; ++r)
        a2[g][r] = fmaf(wx[g], z4[r], bias2[g]);
    }
    if (t < TT - 1) A0 = *(const half8*)(gbase + (t + 1) * HG);
    if (t > 0) {
      barrier_lds();
      const half8 A11 = *(const half8*)(&su.h.hb1[p][col * 72 + quad * 8]);
      const half8 A21 = *(const half8*)(&su.h.hb1[p][col * 72 + 32 + quad * 8]);
      const half8 A12 = *(const half8*)(&su.h.hb2[p][col * 72 + quad * 8]);
      const half8 A22 = *(const half8*)(&su.h.hb2[p][col * 72 + 32 + quad * 8]);
#pragma unroll
      for (int g = 0; g < 4; ++g) {
        a1[g] = __builtin_amdgcn_mfma_f32_16x16x32_f16(A11, Bh1[g][0].v, a1[g], 0, 0, 0);
        a1[g] = __builtin_amdgcn_mfma_f32_16x16x32_f16(A21, Bh1[g][1].v, a1[g], 0, 0, 0);
        a2[g] = __builtin_amdgcn_mfma_f32_16x16x32_f16(A12, Bh2[g][0].v, a2[g], 0, 0, 0);
        a2[g] = __builtin_amdgcn_mfma_f32_16x16x32_f16(A22, Bh2[g][1].v, a2[g], 0, 0, 0);
      }
    }
#pragma unroll
    for (int r = 0; r < 4; ++r) {
      float i1 = sigm2(a1[0][r]), f1 = sigm2(a1[1][r]);
      float g1 = tanh2g(a1[2][r]), o1 = sigm2(a1[3][r]);
      c1[r] = fmaf(f1, c1[r], i1 * g1);
      h1f[r] = o1 * tanh2(c1[r]);
      float i2 = sigm2(a2[0][r]), f2 = sigm2(a2[1][r]);
      float g2 = tanh2g(a2[2][r]), o2 = sigm2(a2[3][r]);
      c2v[r] = fmaf(f2, c2v[r], i2 * g2);
      h2f[r] = o2 * tanh2(c2v[r]);
    }
  }
  // alias hazard: all waves must finish their last hb reads before fcb writes
  barrier_lds();
#pragma unroll
  for (int r = 0; r < 4; ++r) {
    su.fcb[quad * 4 + r][16 * wave + col] = h1f[r];
    su.fcb[quad * 4 + r][64 + 16 * wave + col] = h2f[r];
  }
  barrier_lds();
  if (tid < 64) {
    int pp = tid >> 4, s = tid & 15;
    const f32x4* wr = (const f32x4*)(fc_w + pp * 128);
    const float* hv = su.fcb[s];
    float acc = fc_b[pp];
#pragma unroll
    for (int k = 0; k < 32; ++k) {
      f32x4 w4 = wr[k];
      acc += w4[0] * hv[4 * k] + w4[1] * hv[4 * k + 1] +
             w4[2] * hv[4 * k + 2] + w4[3] * hv[4 * k + 3];
    }
    out[((size_t)(b * PP + pp)) * NN + n0 + s] = acc;
  }
}

extern "C" void kernel_launch(void* const* d_in, const int* in_sizes, int n_in,
                              void* d_out, int out_size, void* d_ws, size_t ws_size,
                              hipStream_t stream) {
  (void)in_sizes; (void)n_in; (void)out_size; (void)ws_size;
  const float* era5  = (const float*)d_in[0];
  const float* zeta  = (const float*)d_in[1];
  const int*   eidx  = (const int*)d_in[2];
  const float* gcn_w = (const float*)d_in[3];
  const float* gcn_b = (const float*)d_in[4];
  const float* w_ih1 = (const float*)d_in[5];
  const float* w_hh1 = (const float*)d_in[6];
  const float* b_ih1 = (const float*)d_in[7];
  const float* b_hh1 = (const float*)d_in[8];
  const float* w_ih2 = (const float*)d_in[9];
  const float* w_hh2 = (const float*)d_in[10];
  const float* b_ih2 = (const float*)d_in[11];
  const float* b_hh2 = (const float*)d_in[12];
  const float* fc_w  = (const float*)d_in[13];
  const float* fc_b  = (const float*)d_in[14];
  float* out = (float*)d_out;

  char* ws = (char*)d_ws;
  int*      cnt  = (int*)(ws);                        // 40 KB
  int*      csr  = (int*)(ws + (64 << 10));           // 3.84 MB
  uint32_t* xt   = (uint32_t*)(ws + (4ull << 20));    // [N][BT][F] fp16, 7.68 MB
  uint32_t* gout = (uint32_t*)(ws + (12ull << 20));   // [B*N][T][HG] fp16, 15.36 MB
  uint32_t* wbuf = (uint32_t*)(ws + (28ull << 20));   // 100*256*4 = 100 KB

  hipMemsetAsync(cnt, 0, NN * sizeof(int), stream);
  k_prepfill<<<FILL_BLKS + PREP_BLKS + 1, 256, 0, stream>>>(
      eidx, cnt, csr, era5, xt, gcn_w,
      w_ih1, w_hh1, b_ih1, b_hh1, w_ih2, w_hh2, b_ih2, b_hh2, wbuf);
  k_gather<<<NN / 4, 256, 0, stream>>>(xt, csr, cnt, gcn_b, wbuf,
                                       (_Float16*)gout);
  k_lstmfc<<<MM / 16, 256, 0, stream>>>((const _Float16*)gout, zeta, wbuf,
                                        fc_w, fc_b, out);
}